// Round 1
// baseline (1812.265 us; speedup 1.0000x reference)
//
#include <hip/hip_runtime.h>
#include <stdint.h>

#define NATOMS 1048576
#define BMOL   16384
#define DIM    128
#define STEPS  8
#define MPB    32              // molecules per block
#define NBLK   (BMOL / MPB)    // 512 blocks, all resident (2/CU)

typedef __attribute__((ext_vector_type(8))) short short8;
typedef __attribute__((ext_vector_type(8))) unsigned short ushort8;
typedef __attribute__((ext_vector_type(4))) float floatx4;

__device__ __forceinline__ float bf2f(unsigned short u) {
    unsigned int x = ((unsigned int)u) << 16;
    float f; __builtin_memcpy(&f, &x, 4); return f;
}
__device__ __forceinline__ unsigned short f2bf(float f) {
    unsigned int x; __builtin_memcpy(&x, &f, 4);
    x = x + 0x7FFFu + ((x >> 16) & 1u);
    return (unsigned short)(x >> 16);
}
__device__ __forceinline__ float sigm(float x) { return 1.f / (1.f + __expf(-x)); }
__device__ __forceinline__ float tanh_fast(float x) {
    float ax = fabsf(x);
    float e = __expf(-2.f * ax);
    float t = (1.f - e) / (1.f + e);
    return x < 0.f ? -t : t;
}

// ---------------------------------------------------------------------------
__global__ void detect_kernel(const unsigned short* a, int* flag) {
    __shared__ int bad;
    int tid = threadIdx.x;
    if (tid == 0) bad = 0;
    __syncthreads();
    unsigned short u = a[tid];
    int e = (u >> 7) & 0xFF;
    if (e > 0x85) atomicAdd(&bad, 1);
    __syncthreads();
    if (tid == 0) flag[0] = (bad == 0) ? 1 : 0;   // 1 = inputs are bf16
}

__global__ void build_offsets_kernel(const int* idx, int* offsets) {
    int b = blockIdx.x * blockDim.x + threadIdx.x;
    if (b > BMOL) return;
    if (b == BMOL) { offsets[BMOL] = NATOMS; return; }
    int lo = 0, hi = NATOMS;
    while (lo < hi) {
        int mid = (lo + hi) >> 1;
        if (idx[mid] < b) lo = mid + 1; else hi = mid;
    }
    offsets[b] = lo;
}

__global__ void conv_wt_kernel(const float* Wf, const unsigned short* Wb,
                               const int* flag, unsigned short* Wt) {
    int t = blockIdx.x * blockDim.x + threadIdx.x;
    if (t >= 512 * 256) return;
    int n = t >> 8, k = t & 255;
    float v = flag[0] ? bf2f(Wb[k * 512 + n]) : Wf[k * 512 + n];
    Wt[n * 256 + k] = f2bf(v);
}

// ---------------------------------------------------------------------------
// Fully fused 8-step recurrence. The recurrence is per-molecule independent:
// block owns 32 molecules; carry/cse in LDS, memory state in registers.
// Only HBM traffic: atom stream (1x fp32 + 7x bf16), W/bias (L2-hot), output.
__global__ __launch_bounds__(256, 2) void fused_kernel(
    const unsigned short* __restrict__ atoms_bf,
    const float* __restrict__ atoms_f32,
    unsigned short* __restrict__ atoms_ws, int have_conv,
    const int* __restrict__ flag, const int* __restrict__ offsets,
    const short* __restrict__ Wt,
    const float* __restrict__ bias_f, const unsigned short* __restrict__ bias_b,
    void* __restrict__ outp)
{
    // stride 264 (+8) -> A-fragment ds_read_b128 is 2-way banked (free)
    __shared__ unsigned short s_cse[MPB][264];   // [carry(128) | readout(128)] bf16
    __shared__ float s_carry[MPB][DIM];          // fp32 carry (score precision)
    __shared__ float s_zq[8][516];               // 8-row gate-exchange buffer
    __shared__ float s_bias[512];
    __shared__ int   s_off[MPB + 1];

    const int tid = threadIdx.x;
    const int wid = tid >> 6, lane = tid & 63;
    const int r0 = blockIdx.x * MPB;
    const int isbf = flag[0];

    if (tid <= MPB) s_off[tid] = offsets[r0 + tid];
    s_bias[tid]       = isbf ? bf2f(bias_b[tid])       : bias_f[tid];
    s_bias[256 + tid] = isbf ? bf2f(bias_b[256 + tid]) : bias_f[256 + tid];

    #pragma unroll
    for (int i = 0; i < 16; i++) {               // zero carry halves
        int ii = tid + i * 256;                  // 0..4095 = 32x128
        int r = ii >> 7, d = ii & 127;
        s_carry[r][d] = 0.f;
        s_cse[r][d] = 0;
    }
    float mem[16];
    #pragma unroll
    for (int i = 0; i < 16; i++) mem[i] = 0.f;

    __syncthreads();

    // ---- step 0: carry==0 -> readout = segment mean (+ fp32->bf16 conv) ----
    if (isbf) {
        const int li = lane & 15, g = lane >> 4;
        for (int t = 0; t < 8; t++) {
            const int m = wid * 8 + t;
            const int s = s_off[m], n = s_off[m + 1] - s;
            float acc[8];
            #pragma unroll
            for (int j = 0; j < 8; j++) acc[j] = 0.f;
            for (int r = g; r < n; r += 4) {
                ushort8 u = *(const ushort8*)(atoms_bf + (size_t)(s + r) * DIM + li * 8);
                #pragma unroll
                for (int j = 0; j < 8; j++) acc[j] += bf2f(u[j]);
            }
            #pragma unroll
            for (int j = 0; j < 8; j++) {
                acc[j] += __shfl_xor(acc[j], 16, 64);
                acc[j] += __shfl_xor(acc[j], 32, 64);
            }
            if (g == 0) {
                float inv = (n > 0) ? 1.f / (float)n : 0.f;
                ushort8 o;
                #pragma unroll
                for (int j = 0; j < 8; j++) o[j] = f2bf(acc[j] * inv);
                *(ushort8*)&s_cse[m][DIM + li * 8] = o;
            }
        }
    } else {
        const int l32 = lane & 31, h = lane >> 5;
        for (int t = 0; t < 8; t++) {
            const int m = wid * 8 + t;
            const int s = s_off[m], n = s_off[m + 1] - s;
            float a0 = 0.f, a1 = 0.f, a2 = 0.f, a3 = 0.f;
            for (int r = h; r < n; r += 2) {
                float4 v = *(const float4*)(atoms_f32 + (size_t)(s + r) * DIM + l32 * 4);
                if (have_conv) {
                    ushort4 o;
                    o.x = f2bf(v.x); o.y = f2bf(v.y); o.z = f2bf(v.z); o.w = f2bf(v.w);
                    *(ushort4*)(atoms_ws + (size_t)(s + r) * DIM + l32 * 4) = o;
                }
                a0 += v.x; a1 += v.y; a2 += v.z; a3 += v.w;
            }
            a0 += __shfl_xor(a0, 32, 64);
            a1 += __shfl_xor(a1, 32, 64);
            a2 += __shfl_xor(a2, 32, 64);
            a3 += __shfl_xor(a3, 32, 64);
            if (h == 0) {
                float inv = (n > 0) ? 1.f / (float)n : 0.f;
                ushort4 o;
                o.x = f2bf(a0 * inv); o.y = f2bf(a1 * inv);
                o.z = f2bf(a2 * inv); o.w = f2bf(a3 * inv);
                *(ushort4*)&s_cse[m][DIM + l32 * 4] = o;
            }
        }
    }

    const unsigned short* abf = isbf ? atoms_bf : (have_conv ? atoms_ws : nullptr);

    for (int it = 0; it < STEPS - 1; it++) {
        __syncthreads();   // s_cse (readout + carry halves) complete

        // ==== z = cse @ W + b (MFMA), then LSTM pointwise ====
        {
            const int lm = lane & 15, quad = lane >> 4;
            const int col0 = wid * 128;
            floatx4 acc[2][8];
            #pragma unroll
            for (int i = 0; i < 2; i++)
                #pragma unroll
                for (int j = 0; j < 8; j++) acc[i][j] = (floatx4){0.f, 0.f, 0.f, 0.f};

            #pragma unroll
            for (int ks = 0; ks < 8; ks++) {
                const int koff = ks * 32 + quad * 8;
                short8 A0 = *(const short8*)&s_cse[lm][koff];
                short8 A1 = *(const short8*)&s_cse[16 + lm][koff];
                #pragma unroll
                for (int nt = 0; nt < 8; nt++) {
                    short8 bw = *(const short8*)(Wt + (size_t)(col0 + nt * 16 + lm) * 256 + koff);
                    acc[0][nt] = __builtin_amdgcn_mfma_f32_16x16x32_bf16(A0, bw, acc[0][nt], 0, 0, 0);
                    acc[1][nt] = __builtin_amdgcn_mfma_f32_16x16x32_bf16(A1, bw, acc[1][nt], 0, 0, 0);
                }
            }
            // gate exchange in four 8-row quarters (16.5 KB LDS instead of 66 KB)
            const int d = tid & 127, rh = tid >> 7;
            #pragma unroll
            for (int qq = 0; qq < 4; qq++) {
                const int mt = qq >> 1, qh = qq & 1;
                if ((quad >> 1) == qh) {    // rows quad*4+i in [qh*8, qh*8+8)
                    #pragma unroll
                    for (int nt = 0; nt < 8; nt++) {
                        const int col = col0 + nt * 16 + lm;
                        const float bv = s_bias[col];
                        #pragma unroll
                        for (int i = 0; i < 4; i++)
                            s_zq[(quad & 1) * 4 + i][col] = acc[mt][nt][i] + bv;
                    }
                }
                __syncthreads();
                #pragma unroll
                for (int k = 0; k < 4; k++) {
                    const int lr = rh + k * 2;          // 0..7
                    const int r = qq * 8 + lr;          // global row in block
                    float zu = s_zq[lr][d];
                    float zf = s_zq[lr][128 + d];
                    float zc = s_zq[lr][256 + d];
                    float zo = s_zq[lr][384 + d];
                    float mv = sigm(zf) * mem[qq * 4 + k] + sigm(zu) * tanh_fast(zc);
                    mem[qq * 4 + k] = mv;
                    float cs = sigm(zo) * tanh_fast(mv);
                    s_carry[r][d] = cs;
                    s_cse[r][d] = f2bf(cs);
                }
                __syncthreads();
            }
        }

        // ==== attention for step it+1 (wave-local, no block syncs) ====
        const int last = (it == STEPS - 2);
        if (abf) {
            const int li = lane & 15, g = lane >> 4;
            for (int t = 0; t < 8; t++) {
                const int m = wid * 8 + t;
                const int s = s_off[m], n = s_off[m + 1] - s;
                float c[8];
                {
                    float4 c0 = *(const float4*)&s_carry[m][li * 8];
                    float4 c1 = *(const float4*)&s_carry[m][li * 8 + 4];
                    c[0] = c0.x; c[1] = c0.y; c[2] = c0.z; c[3] = c0.w;
                    c[4] = c1.x; c[5] = c1.y; c[6] = c1.z; c[7] = c1.w;
                }
                float acc[8];
                #pragma unroll
                for (int j = 0; j < 8; j++) acc[j] = 0.f;
                float mx = -INFINITY, l = 0.f;
                for (int r = g; r < n; r += 4) {
                    ushort8 u = *(const ushort8*)(abf + (size_t)(s + r) * DIM + li * 8);
                    float x[8];
                    #pragma unroll
                    for (int j = 0; j < 8; j++) x[j] = bf2f(u[j]);
                    float pd = x[0]*c[0] + x[1]*c[1] + x[2]*c[2] + x[3]*c[3]
                             + x[4]*c[4] + x[5]*c[5] + x[6]*c[6] + x[7]*c[7];
                    pd += __shfl_xor(pd, 1, 64);
                    pd += __shfl_xor(pd, 2, 64);
                    pd += __shfl_xor(pd, 4, 64);
                    pd += __shfl_xor(pd, 8, 64);
                    // branchless online softmax (no wave divergence)
                    float nm = fmaxf(mx, pd);
                    float sa = __expf(mx - nm);   // first iter: exp(-inf)=0
                    float ex = __expf(pd - nm);
                    l = l * sa + ex;
                    #pragma unroll
                    for (int j = 0; j < 8; j++) acc[j] = acc[j] * sa + ex * x[j];
                    mx = nm;
                }
                // merge the 4 16-lane groups (guarded against -inf/-inf)
                for (int off = 16; off < 64; off <<= 1) {
                    float m2 = __shfl_xor(mx, off, 64);
                    float l2 = __shfl_xor(l, off, 64);
                    float nm = fmaxf(mx, m2);
                    float sa = (mx == nm) ? 1.f : __expf(mx - nm);
                    float sb = (m2 == nm) ? 1.f : __expf(m2 - nm);
                    l = l * sa + l2 * sb;
                    #pragma unroll
                    for (int j = 0; j < 8; j++) {
                        float a2 = __shfl_xor(acc[j], off, 64);
                        acc[j] = acc[j] * sa + a2 * sb;
                    }
                    mx = nm;
                }
                float invl = (l > 0.f) ? 1.f / l : 0.f;
                if (g == 0) {
                    if (!last) {
                        ushort8 o;
                        #pragma unroll
                        for (int j = 0; j < 8; j++) o[j] = f2bf(acc[j] * invl);
                        *(ushort8*)&s_cse[m][DIM + li * 8] = o;
                    } else {
                        const size_t gm = (size_t)(r0 + m) * 256;
                        if (isbf) {
                            unsigned short* ob = (unsigned short*)outp;
                            ushort8 oc, orr;
                            #pragma unroll
                            for (int j = 0; j < 8; j++) {
                                oc[j]  = f2bf(c[j]);
                                orr[j] = f2bf(acc[j] * invl);
                            }
                            *(ushort8*)(ob + gm + li * 8) = oc;
                            *(ushort8*)(ob + gm + DIM + li * 8) = orr;
                        } else {
                            float* of = (float*)outp;
                            *(float4*)(of + gm + li * 8)     = make_float4(c[0], c[1], c[2], c[3]);
                            *(float4*)(of + gm + li * 8 + 4) = make_float4(c[4], c[5], c[6], c[7]);
                            *(float4*)(of + gm + DIM + li * 8) =
                                make_float4(acc[0]*invl, acc[1]*invl, acc[2]*invl, acc[3]*invl);
                            *(float4*)(of + gm + DIM + li * 8 + 4) =
                                make_float4(acc[4]*invl, acc[5]*invl, acc[6]*invl, acc[7]*invl);
                        }
                    }
                }
            }
        } else {
            // fp32-direct fallback (no conversion buffer)
            const int l32 = lane & 31, h = lane >> 5;
            for (int t = 0; t < 8; t++) {
                const int m = wid * 8 + t;
                const int s = s_off[m], n = s_off[m + 1] - s;
                float4 c4 = *(const float4*)&s_carry[m][l32 * 4];
                float a0 = 0.f, a1 = 0.f, a2 = 0.f, a3 = 0.f;
                float mx = -INFINITY, l = 0.f;
                for (int r = h; r < n; r += 2) {
                    float4 v = *(const float4*)(atoms_f32 + (size_t)(s + r) * DIM + l32 * 4);
                    float pd = v.x*c4.x + v.y*c4.y + v.z*c4.z + v.w*c4.w;
                    pd += __shfl_xor(pd, 1, 64);
                    pd += __shfl_xor(pd, 2, 64);
                    pd += __shfl_xor(pd, 4, 64);
                    pd += __shfl_xor(pd, 8, 64);
                    pd += __shfl_xor(pd, 16, 64);
                    float nm = fmaxf(mx, pd);
                    float sa = __expf(mx - nm);
                    float ex = __expf(pd - nm);
                    l = l * sa + ex;
                    a0 = a0 * sa + ex * v.x; a1 = a1 * sa + ex * v.y;
                    a2 = a2 * sa + ex * v.z; a3 = a3 * sa + ex * v.w;
                    mx = nm;
                }
                {
                    float m2 = __shfl_xor(mx, 32, 64);
                    float l2 = __shfl_xor(l, 32, 64);
                    float nm = fmaxf(mx, m2);
                    float sa = (mx == nm) ? 1.f : __expf(mx - nm);
                    float sb = (m2 == nm) ? 1.f : __expf(m2 - nm);
                    l = l * sa + l2 * sb;
                    float b0 = __shfl_xor(a0, 32, 64), b1 = __shfl_xor(a1, 32, 64);
                    float b2 = __shfl_xor(a2, 32, 64), b3 = __shfl_xor(a3, 32, 64);
                    a0 = a0 * sa + b0 * sb; a1 = a1 * sa + b1 * sb;
                    a2 = a2 * sa + b2 * sb; a3 = a3 * sa + b3 * sb;
                }
                float invl = (l > 0.f) ? 1.f / l : 0.f;
                if (h == 0) {
                    if (!last) {
                        ushort4 o;
                        o.x = f2bf(a0 * invl); o.y = f2bf(a1 * invl);
                        o.z = f2bf(a2 * invl); o.w = f2bf(a3 * invl);
                        *(ushort4*)&s_cse[m][DIM + l32 * 4] = o;
                    } else {
                        float* of = (float*)outp;
                        const size_t gm = (size_t)(r0 + m) * 256;
                        *(float4*)(of + gm + l32 * 4) = c4;
                        *(float4*)(of + gm + DIM + l32 * 4) =
                            make_float4(a0*invl, a1*invl, a2*invl, a3*invl);
                    }
                }
            }
        }
    }
}

// ---------------------------------------------------------------------------
extern "C" void kernel_launch(void* const* d_in, const int* in_sizes, int n_in,
                              void* d_out, int out_size, void* d_ws, size_t ws_size,
                              hipStream_t stream)
{
    const void* atoms_raw = d_in[0];
    const int*  idx       = (const int*)d_in[1];
    const void* W_raw     = d_in[2];
    const void* bias_raw  = d_in[3];

    char* ws = (char*)d_ws;
    size_t off = 0;
    auto alloc = [&](size_t bytes) {
        size_t p = off;
        off = (off + bytes + 255) & ~(size_t)255;
        return p;
    };
    int*            flag    = (int*)(ws + alloc(4));
    int*            offsets = (int*)(ws + alloc((BMOL + 1) * sizeof(int)));
    unsigned short* Wt      = (unsigned short*)(ws + alloc(512 * 256 * 2));
    size_t conv_off = alloc((size_t)NATOMS * DIM * 2);
    int have_conv = (ws_size >= off) ? 1 : 0;
    unsigned short* atoms_ws = (unsigned short*)(ws + conv_off);

    detect_kernel<<<1, 256, 0, stream>>>((const unsigned short*)atoms_raw, flag);
    build_offsets_kernel<<<(BMOL + 1 + 255) / 256, 256, 0, stream>>>(idx, offsets);
    conv_wt_kernel<<<512, 256, 0, stream>>>((const float*)W_raw,
                                            (const unsigned short*)W_raw, flag, Wt);
    fused_kernel<<<NBLK, 256, 0, stream>>>(
        (const unsigned short*)atoms_raw, (const float*)atoms_raw,
        atoms_ws, have_conv, flag, offsets, (const short*)Wt,
        (const float*)bias_raw, (const unsigned short*)bias_raw, d_out);
}

// Round 2
// 1550.063 us; speedup vs baseline: 1.1692x; 1.1692x over previous
//
#include <hip/hip_runtime.h>
#include <stdint.h>

#define NATOMS 1048576
#define BMOL   16384
#define DIM    128
#define STEPS  8
#define MPB    16              // molecules per block
#define NBLK   (BMOL / MPB)    // 1024 blocks -> 4 blocks/CU

typedef __attribute__((ext_vector_type(8))) short short8;
typedef __attribute__((ext_vector_type(8))) unsigned short ushort8;
typedef __attribute__((ext_vector_type(4))) float floatx4;

__device__ __forceinline__ float bf2f(unsigned short u) {
    unsigned int x = ((unsigned int)u) << 16;
    float f; __builtin_memcpy(&f, &x, 4); return f;
}
__device__ __forceinline__ unsigned short f2bf(float f) {
    unsigned int x; __builtin_memcpy(&x, &f, 4);
    x = x + 0x7FFFu + ((x >> 16) & 1u);
    return (unsigned short)(x >> 16);
}
__device__ __forceinline__ float sigm(float x) { return 1.f / (1.f + __expf(-x)); }
__device__ __forceinline__ float tanh_fast(float x) {
    float ax = fabsf(x);
    float e = __expf(-2.f * ax);
    float t = (1.f - e) / (1.f + e);
    return x < 0.f ? -t : t;
}

// ---------------------------------------------------------------------------
__global__ void detect_kernel(const unsigned short* a, int* flag) {
    __shared__ int bad;
    int tid = threadIdx.x;
    if (tid == 0) bad = 0;
    __syncthreads();
    unsigned short u = a[tid];
    int e = (u >> 7) & 0xFF;
    if (e > 0x85) atomicAdd(&bad, 1);
    __syncthreads();
    if (tid == 0) flag[0] = (bad == 0) ? 1 : 0;   // 1 = inputs are bf16
}

__global__ void build_offsets_kernel(const int* idx, int* offsets) {
    int b = blockIdx.x * blockDim.x + threadIdx.x;
    if (b > BMOL) return;
    if (b == BMOL) { offsets[BMOL] = NATOMS; return; }
    int lo = 0, hi = NATOMS;
    while (lo < hi) {
        int mid = (lo + hi) >> 1;
        if (idx[mid] < b) lo = mid + 1; else hi = mid;
    }
    offsets[b] = lo;
}

__global__ void conv_wt_kernel(const float* Wf, const unsigned short* Wb,
                               const int* flag, unsigned short* Wt) {
    int t = blockIdx.x * blockDim.x + threadIdx.x;
    if (t >= 512 * 256) return;
    int n = t >> 8, k = t & 255;
    float v = flag[0] ? bf2f(Wb[k * 512 + n]) : Wf[k * 512 + n];
    Wt[n * 256 + k] = f2bf(v);
}

// ---------------------------------------------------------------------------
// Fully fused 8-step recurrence; block owns 16 molecules.
// ~35 KB LDS + VGPR<=128 -> 4 blocks/CU (16 waves/CU).
// Attention streams use 2 independent online-softmax states per 16-lane
// group (rows r and r+4 in flight) for 2x memory-level parallelism.
__global__ __launch_bounds__(256, 4) void fused_kernel(
    const unsigned short* __restrict__ atoms_bf,
    const float* __restrict__ atoms_f32,
    unsigned short* __restrict__ atoms_ws, int have_conv,
    const int* __restrict__ flag, const int* __restrict__ offsets,
    const short* __restrict__ Wt,
    const float* __restrict__ bias_f, const unsigned short* __restrict__ bias_b,
    void* __restrict__ outp)
{
    __shared__ unsigned short s_cse[MPB][264];   // [carry(128) | readout(128)] bf16
    __shared__ float s_carry[MPB][DIM];          // fp32 carry
    __shared__ float s_zq[8][516];               // 8-row gate-exchange buffer
    __shared__ float s_bias[512];
    __shared__ int   s_off[MPB + 1];

    const int tid = threadIdx.x;
    const int wid = tid >> 6, lane = tid & 63;
    const int r0 = blockIdx.x * MPB;
    const int isbf = flag[0];

    if (tid <= MPB) s_off[tid] = offsets[r0 + tid];
    s_bias[tid]       = isbf ? bf2f(bias_b[tid])       : bias_f[tid];
    s_bias[256 + tid] = isbf ? bf2f(bias_b[256 + tid]) : bias_f[256 + tid];

    #pragma unroll
    for (int i = 0; i < 8; i++) {                // zero 16x128 carry halves
        int ii = tid + i * 256;
        int r = ii >> 7, d = ii & 127;
        s_carry[r][d] = 0.f;
        s_cse[r][d] = 0;
    }
    float mem[8];
    #pragma unroll
    for (int i = 0; i < 8; i++) mem[i] = 0.f;

    __syncthreads();

    // ---- step 0: carry==0 -> readout = segment mean (+ fp32->bf16 conv) ----
    if (isbf) {
        const int li = lane & 15, g = lane >> 4;
        for (int t = 0; t < 4; t++) {
            const int m = wid * 4 + t;
            const int s = s_off[m], n = s_off[m + 1] - s;
            float a0[8], a1[8];
            #pragma unroll
            for (int j = 0; j < 8; j++) { a0[j] = 0.f; a1[j] = 0.f; }
            int r = g;
            for (; r + 4 < n; r += 8) {
                ushort8 u0 = *(const ushort8*)(atoms_bf + (size_t)(s + r) * DIM + li * 8);
                ushort8 u1 = *(const ushort8*)(atoms_bf + (size_t)(s + r + 4) * DIM + li * 8);
                #pragma unroll
                for (int j = 0; j < 8; j++) { a0[j] += bf2f(u0[j]); a1[j] += bf2f(u1[j]); }
            }
            if (r < n) {
                ushort8 u0 = *(const ushort8*)(atoms_bf + (size_t)(s + r) * DIM + li * 8);
                #pragma unroll
                for (int j = 0; j < 8; j++) a0[j] += bf2f(u0[j]);
            }
            #pragma unroll
            for (int j = 0; j < 8; j++) {
                a0[j] += a1[j];
                a0[j] += __shfl_xor(a0[j], 16, 64);
                a0[j] += __shfl_xor(a0[j], 32, 64);
            }
            if (g == 0) {
                float inv = (n > 0) ? 1.f / (float)n : 0.f;
                ushort8 o;
                #pragma unroll
                for (int j = 0; j < 8; j++) o[j] = f2bf(a0[j] * inv);
                *(ushort8*)&s_cse[m][DIM + li * 8] = o;
            }
        }
    } else {
        const int l32 = lane & 31, h = lane >> 5;
        for (int t = 0; t < 4; t++) {
            const int m = wid * 4 + t;
            const int s = s_off[m], n = s_off[m + 1] - s;
            float a0[4], a1[4];
            #pragma unroll
            for (int j = 0; j < 4; j++) { a0[j] = 0.f; a1[j] = 0.f; }
            int r = h;
            for (; r + 2 < n; r += 4) {
                float4 v0 = *(const float4*)(atoms_f32 + (size_t)(s + r) * DIM + l32 * 4);
                float4 v1 = *(const float4*)(atoms_f32 + (size_t)(s + r + 2) * DIM + l32 * 4);
                if (have_conv) {
                    ushort4 o0, o1;
                    o0.x = f2bf(v0.x); o0.y = f2bf(v0.y); o0.z = f2bf(v0.z); o0.w = f2bf(v0.w);
                    o1.x = f2bf(v1.x); o1.y = f2bf(v1.y); o1.z = f2bf(v1.z); o1.w = f2bf(v1.w);
                    *(ushort4*)(atoms_ws + (size_t)(s + r) * DIM + l32 * 4) = o0;
                    *(ushort4*)(atoms_ws + (size_t)(s + r + 2) * DIM + l32 * 4) = o1;
                }
                a0[0] += v0.x; a0[1] += v0.y; a0[2] += v0.z; a0[3] += v0.w;
                a1[0] += v1.x; a1[1] += v1.y; a1[2] += v1.z; a1[3] += v1.w;
            }
            if (r < n) {
                float4 v0 = *(const float4*)(atoms_f32 + (size_t)(s + r) * DIM + l32 * 4);
                if (have_conv) {
                    ushort4 o0;
                    o0.x = f2bf(v0.x); o0.y = f2bf(v0.y); o0.z = f2bf(v0.z); o0.w = f2bf(v0.w);
                    *(ushort4*)(atoms_ws + (size_t)(s + r) * DIM + l32 * 4) = o0;
                }
                a0[0] += v0.x; a0[1] += v0.y; a0[2] += v0.z; a0[3] += v0.w;
            }
            #pragma unroll
            for (int j = 0; j < 4; j++) {
                a0[j] += a1[j];
                a0[j] += __shfl_xor(a0[j], 32, 64);
            }
            if (h == 0) {
                float inv = (n > 0) ? 1.f / (float)n : 0.f;
                ushort4 o;
                o.x = f2bf(a0[0] * inv); o.y = f2bf(a0[1] * inv);
                o.z = f2bf(a0[2] * inv); o.w = f2bf(a0[3] * inv);
                *(ushort4*)&s_cse[m][DIM + l32 * 4] = o;
            }
        }
    }

    const unsigned short* abf = isbf ? atoms_bf : (have_conv ? atoms_ws : nullptr);

    for (int it = 0; it < STEPS - 1; it++) {
        __syncthreads();   // s_cse (readout + carry halves) complete

        // ==== z = cse @ W + b (MFMA), then LSTM pointwise ====
        {
            const int lm = lane & 15, quad = lane >> 4;
            const int col0 = wid * 128;
            floatx4 acc[8];
            #pragma unroll
            for (int j = 0; j < 8; j++) acc[j] = (floatx4){0.f, 0.f, 0.f, 0.f};

            #pragma unroll
            for (int ks = 0; ks < 8; ks++) {
                const int koff = ks * 32 + quad * 8;
                short8 A0 = *(const short8*)&s_cse[lm][koff];
                #pragma unroll
                for (int nt = 0; nt < 8; nt++) {
                    short8 bw = *(const short8*)(Wt + (size_t)(col0 + nt * 16 + lm) * 256 + koff);
                    acc[nt] = __builtin_amdgcn_mfma_f32_16x16x32_bf16(A0, bw, acc[nt], 0, 0, 0);
                }
            }
            // gate exchange in two 8-row quarters
            const int d = tid & 127, rh = tid >> 7;
            #pragma unroll
            for (int qq = 0; qq < 2; qq++) {
                if ((quad >> 1) == qq) {    // rows quad*4+i in [qq*8, qq*8+8)
                    #pragma unroll
                    for (int nt = 0; nt < 8; nt++) {
                        const int col = col0 + nt * 16 + lm;
                        const float bv = s_bias[col];
                        #pragma unroll
                        for (int i = 0; i < 4; i++)
                            s_zq[(quad & 1) * 4 + i][col] = acc[nt][i] + bv;
                    }
                }
                __syncthreads();
                #pragma unroll
                for (int k = 0; k < 4; k++) {
                    const int lr = rh + k * 2;          // 0..7
                    const int r = qq * 8 + lr;          // row in block
                    float zu = s_zq[lr][d];
                    float zf = s_zq[lr][128 + d];
                    float zc = s_zq[lr][256 + d];
                    float zo = s_zq[lr][384 + d];
                    float mv = sigm(zf) * mem[qq * 4 + k] + sigm(zu) * tanh_fast(zc);
                    mem[qq * 4 + k] = mv;
                    float cs = sigm(zo) * tanh_fast(mv);
                    s_carry[r][d] = cs;
                    s_cse[r][d] = f2bf(cs);
                }
                __syncthreads();
            }
        }

        // ==== attention for step it+1 (wave-local, no block syncs) ====
        const int last = (it == STEPS - 2);
        if (abf) {
            const int li = lane & 15, g = lane >> 4;
            for (int t = 0; t < 4; t++) {
                const int m = wid * 4 + t;
                const int s = s_off[m], n = s_off[m + 1] - s;
                float c[8];
                {
                    float4 c0 = *(const float4*)&s_carry[m][li * 8];
                    float4 c1 = *(const float4*)&s_carry[m][li * 8 + 4];
                    c[0] = c0.x; c[1] = c0.y; c[2] = c0.z; c[3] = c0.w;
                    c[4] = c1.x; c[5] = c1.y; c[6] = c1.z; c[7] = c1.w;
                }
                float ac0[8], ac1[8];
                #pragma unroll
                for (int j = 0; j < 8; j++) { ac0[j] = 0.f; ac1[j] = 0.f; }
                float mx0 = -INFINITY, l0 = 0.f;
                float mx1 = -INFINITY, l1 = 0.f;
                int r = g;
                for (; r + 4 < n; r += 8) {
                    ushort8 u0 = *(const ushort8*)(abf + (size_t)(s + r) * DIM + li * 8);
                    ushort8 u1 = *(const ushort8*)(abf + (size_t)(s + r + 4) * DIM + li * 8);
                    float x0[8], x1[8];
                    #pragma unroll
                    for (int j = 0; j < 8; j++) { x0[j] = bf2f(u0[j]); x1[j] = bf2f(u1[j]); }
                    float p0 = x0[0]*c[0] + x0[1]*c[1] + x0[2]*c[2] + x0[3]*c[3]
                             + x0[4]*c[4] + x0[5]*c[5] + x0[6]*c[6] + x0[7]*c[7];
                    float p1 = x1[0]*c[0] + x1[1]*c[1] + x1[2]*c[2] + x1[3]*c[3]
                             + x1[4]*c[4] + x1[5]*c[5] + x1[6]*c[6] + x1[7]*c[7];
                    p0 += __shfl_xor(p0, 1, 64);  p1 += __shfl_xor(p1, 1, 64);
                    p0 += __shfl_xor(p0, 2, 64);  p1 += __shfl_xor(p1, 2, 64);
                    p0 += __shfl_xor(p0, 4, 64);  p1 += __shfl_xor(p1, 4, 64);
                    p0 += __shfl_xor(p0, 8, 64);  p1 += __shfl_xor(p1, 8, 64);
                    // branchless online softmax, two independent chains
                    float nm0 = fmaxf(mx0, p0);
                    float sa0 = __expf(mx0 - nm0);
                    float ex0 = __expf(p0 - nm0);
                    l0 = l0 * sa0 + ex0;
                    #pragma unroll
                    for (int j = 0; j < 8; j++) ac0[j] = ac0[j] * sa0 + ex0 * x0[j];
                    mx0 = nm0;
                    float nm1 = fmaxf(mx1, p1);
                    float sa1 = __expf(mx1 - nm1);
                    float ex1 = __expf(p1 - nm1);
                    l1 = l1 * sa1 + ex1;
                    #pragma unroll
                    for (int j = 0; j < 8; j++) ac1[j] = ac1[j] * sa1 + ex1 * x1[j];
                    mx1 = nm1;
                }
                if (r < n) {
                    ushort8 u0 = *(const ushort8*)(abf + (size_t)(s + r) * DIM + li * 8);
                    float x0[8];
                    #pragma unroll
                    for (int j = 0; j < 8; j++) x0[j] = bf2f(u0[j]);
                    float p0 = x0[0]*c[0] + x0[1]*c[1] + x0[2]*c[2] + x0[3]*c[3]
                             + x0[4]*c[4] + x0[5]*c[5] + x0[6]*c[6] + x0[7]*c[7];
                    p0 += __shfl_xor(p0, 1, 64);
                    p0 += __shfl_xor(p0, 2, 64);
                    p0 += __shfl_xor(p0, 4, 64);
                    p0 += __shfl_xor(p0, 8, 64);
                    float nm0 = fmaxf(mx0, p0);
                    float sa0 = __expf(mx0 - nm0);
                    float ex0 = __expf(p0 - nm0);
                    l0 = l0 * sa0 + ex0;
                    #pragma unroll
                    for (int j = 0; j < 8; j++) ac0[j] = ac0[j] * sa0 + ex0 * x0[j];
                    mx0 = nm0;
                }
                // merge state1 into state0 (guarded for -inf)
                {
                    float nm = fmaxf(mx0, mx1);
                    float sa = (mx0 == nm) ? 1.f : __expf(mx0 - nm);
                    float sb = (mx1 == nm) ? 1.f : __expf(mx1 - nm);
                    l0 = l0 * sa + l1 * sb;
                    #pragma unroll
                    for (int j = 0; j < 8; j++) ac0[j] = ac0[j] * sa + ac1[j] * sb;
                    mx0 = nm;
                }
                // merge the 4 16-lane groups
                for (int off = 16; off < 64; off <<= 1) {
                    float m2 = __shfl_xor(mx0, off, 64);
                    float l2 = __shfl_xor(l0, off, 64);
                    float nm = fmaxf(mx0, m2);
                    float sa = (mx0 == nm) ? 1.f : __expf(mx0 - nm);
                    float sb = (m2 == nm) ? 1.f : __expf(m2 - nm);
                    l0 = l0 * sa + l2 * sb;
                    #pragma unroll
                    for (int j = 0; j < 8; j++) {
                        float a2 = __shfl_xor(ac0[j], off, 64);
                        ac0[j] = ac0[j] * sa + a2 * sb;
                    }
                    mx0 = nm;
                }
                float invl = (l0 > 0.f) ? 1.f / l0 : 0.f;
                if (g == 0) {
                    if (!last) {
                        ushort8 o;
                        #pragma unroll
                        for (int j = 0; j < 8; j++) o[j] = f2bf(ac0[j] * invl);
                        *(ushort8*)&s_cse[m][DIM + li * 8] = o;
                    } else {
                        const size_t gm = (size_t)(r0 + m) * 256;
                        if (isbf) {
                            unsigned short* ob = (unsigned short*)outp;
                            ushort8 oc, orr;
                            #pragma unroll
                            for (int j = 0; j < 8; j++) {
                                oc[j]  = f2bf(c[j]);
                                orr[j] = f2bf(ac0[j] * invl);
                            }
                            *(ushort8*)(ob + gm + li * 8) = oc;
                            *(ushort8*)(ob + gm + DIM + li * 8) = orr;
                        } else {
                            float* of = (float*)outp;
                            *(float4*)(of + gm + li * 8)     = make_float4(c[0], c[1], c[2], c[3]);
                            *(float4*)(of + gm + li * 8 + 4) = make_float4(c[4], c[5], c[6], c[7]);
                            *(float4*)(of + gm + DIM + li * 8) =
                                make_float4(ac0[0]*invl, ac0[1]*invl, ac0[2]*invl, ac0[3]*invl);
                            *(float4*)(of + gm + DIM + li * 8 + 4) =
                                make_float4(ac0[4]*invl, ac0[5]*invl, ac0[6]*invl, ac0[7]*invl);
                        }
                    }
                }
            }
        } else {
            // fp32-direct fallback (no conversion buffer)
            const int l32 = lane & 31, h = lane >> 5;
            for (int t = 0; t < 4; t++) {
                const int m = wid * 4 + t;
                const int s = s_off[m], n = s_off[m + 1] - s;
                float4 c4 = *(const float4*)&s_carry[m][l32 * 4];
                float a0 = 0.f, a1 = 0.f, a2 = 0.f, a3 = 0.f;
                float mx = -INFINITY, l = 0.f;
                for (int r = h; r < n; r += 2) {
                    float4 v = *(const float4*)(atoms_f32 + (size_t)(s + r) * DIM + l32 * 4);
                    float pd = v.x*c4.x + v.y*c4.y + v.z*c4.z + v.w*c4.w;
                    pd += __shfl_xor(pd, 1, 64);
                    pd += __shfl_xor(pd, 2, 64);
                    pd += __shfl_xor(pd, 4, 64);
                    pd += __shfl_xor(pd, 8, 64);
                    pd += __shfl_xor(pd, 16, 64);
                    float nm = fmaxf(mx, pd);
                    float sa = __expf(mx - nm);
                    float ex = __expf(pd - nm);
                    l = l * sa + ex;
                    a0 = a0 * sa + ex * v.x; a1 = a1 * sa + ex * v.y;
                    a2 = a2 * sa + ex * v.z; a3 = a3 * sa + ex * v.w;
                    mx = nm;
                }
                {
                    float m2 = __shfl_xor(mx, 32, 64);
                    float l2 = __shfl_xor(l, 32, 64);
                    float nm = fmaxf(mx, m2);
                    float sa = (mx == nm) ? 1.f : __expf(mx - nm);
                    float sb = (m2 == nm) ? 1.f : __expf(m2 - nm);
                    l = l * sa + l2 * sb;
                    float b0 = __shfl_xor(a0, 32, 64), b1 = __shfl_xor(a1, 32, 64);
                    float b2 = __shfl_xor(a2, 32, 64), b3 = __shfl_xor(a3, 32, 64);
                    a0 = a0 * sa + b0 * sb; a1 = a1 * sa + b1 * sb;
                    a2 = a2 * sa + b2 * sb; a3 = a3 * sa + b3 * sb;
                }
                float invl = (l > 0.f) ? 1.f / l : 0.f;
                if (h == 0) {
                    if (!last) {
                        ushort4 o;
                        o.x = f2bf(a0 * invl); o.y = f2bf(a1 * invl);
                        o.z = f2bf(a2 * invl); o.w = f2bf(a3 * invl);
                        *(ushort4*)&s_cse[m][DIM + l32 * 4] = o;
                    } else {
                        float* of = (float*)outp;
                        const size_t gm = (size_t)(r0 + m) * 256;
                        *(float4*)(of + gm + l32 * 4) = c4;
                        *(float4*)(of + gm + DIM + l32 * 4) =
                            make_float4(a0*invl, a1*invl, a2*invl, a3*invl);
                    }
                }
            }
        }
    }
}

// ---------------------------------------------------------------------------
extern "C" void kernel_launch(void* const* d_in, const int* in_sizes, int n_in,
                              void* d_out, int out_size, void* d_ws, size_t ws_size,
                              hipStream_t stream)
{
    const void* atoms_raw = d_in[0];
    const int*  idx       = (const int*)d_in[1];
    const void* W_raw     = d_in[2];
    const void* bias_raw  = d_in[3];

    char* ws = (char*)d_ws;
    size_t off = 0;
    auto alloc = [&](size_t bytes) {
        size_t p = off;
        off = (off + bytes + 255) & ~(size_t)255;
        return p;
    };
    int*            flag    = (int*)(ws + alloc(4));
    int*            offsets = (int*)(ws + alloc((BMOL + 1) * sizeof(int)));
    unsigned short* Wt      = (unsigned short*)(ws + alloc(512 * 256 * 2));
    size_t conv_off = alloc((size_t)NATOMS * DIM * 2);
    int have_conv = (ws_size >= off) ? 1 : 0;
    unsigned short* atoms_ws = (unsigned short*)(ws + conv_off);

    detect_kernel<<<1, 256, 0, stream>>>((const unsigned short*)atoms_raw, flag);
    build_offsets_kernel<<<(BMOL + 1 + 255) / 256, 256, 0, stream>>>(idx, offsets);
    conv_wt_kernel<<<512, 256, 0, stream>>>((const float*)W_raw,
                                            (const unsigned short*)W_raw, flag, Wt);
    fused_kernel<<<NBLK, 256, 0, stream>>>(
        (const unsigned short*)atoms_raw, (const float*)atoms_raw,
        atoms_ws, have_conv, flag, offsets, (const short*)Wt,
        (const float*)bias_raw, (const unsigned short*)bias_raw, d_out);
}